// Round 21
// baseline (316.685 us; speedup 1.0000x reference)
//
#include <hip/hip_runtime.h>

typedef __bf16 bf16;
typedef __bf16 bf16x4 __attribute__((ext_vector_type(4)));
typedef __bf16 bf16x8 __attribute__((ext_vector_type(8)));
typedef float  f32x4  __attribute__((ext_vector_type(4)));
typedef float  f32x16 __attribute__((ext_vector_type(16)));

#define BATCH  2
#define SEQ    2048
#define ROWS   (BATCH*SEQ)     // 4096
#define DMODEL 1024
#define DINNER 2048
#define DSTATE 16
#define NH     32
#define HD     64
#define CONVD  2080
#define DPROJ  4160
#define DMLP   4096
#define DTOFF  (DINNER + CONVD)   // 4128
#define CS     64                 // scan chunk size
#define NCHUNK (SEQ/CS)           // 32
#define NSPLIT 2                  // split-K slices for N=1024 GEMMs

__device__ __forceinline__ float sigmoidf_(float x) { return 1.f / (1.f + expf(-x)); }

__device__ __forceinline__ float blockSum256(float v, int tid) {
    #pragma unroll
    for (int o = 32; o > 0; o >>= 1) v += __shfl_down(v, o);
    __shared__ float sb[4];
    if ((tid & 63) == 0) sb[tid >> 6] = v;
    __syncthreads();
    return sb[0] + sb[1] + sb[2] + sb[3];
}

__device__ __forceinline__ void gload_lds16(const bf16* g, bf16* l) {
    __builtin_amdgcn_global_load_lds((const __attribute__((address_space(1))) void*)g,
                                     (__attribute__((address_space(3))) void*)l, 16, 0, 0);
}

// bijective XCD-chunk swizzle (m204)
__device__ __forceinline__ int xcd_swz(int orig, int nwg) {
    const int q = nwg >> 3, r = nwg & 7;
    const int x = orig & 7, i = orig >> 3;
    return (x < r ? x * (q + 1) : r * (q + 1) + (x - r) * q) + i;
}

// --- merged front kernel: 4 weight transposes + rmsnorm1, segmented 1D grid ---
#define TSEG0 4160
#define TSEG1 (TSEG0 + 2048)   // 6208
#define TSEG2 (TSEG1 + 4096)   // 10304
#define TSEG3 (TSEG2 + 4096)   // 14400
#define TSEG4 (TSEG3 + ROWS)   // 18496  (rmsnorm1 rows)
__global__ __launch_bounds__(256) void front_k(
    const float* __restrict__ s0, bf16* __restrict__ d0,
    const float* __restrict__ s1, bf16* __restrict__ d1,
    const float* __restrict__ s2, bf16* __restrict__ d2,
    const float* __restrict__ s3, bf16* __restrict__ d3,
    const float* __restrict__ x,  const float* __restrict__ n1w,
    bf16* __restrict__ h1)
{
    const int gb = blockIdx.x;
    const int tx = threadIdx.x, ty = threadIdx.y;   // block (32,8)
    if (gb >= TSEG3) {
        // ---- rmsnorm1: one row per block, flat 256 threads ----
        const int row = gb - TSEG3;
        const int tid = ty * 32 + tx;
        const float4 v = *(const float4*)(x + (size_t)row * DMODEL + tid * 4);
        float f[4] = { v.x, v.y, v.z, v.w };
        float ss = f[0]*f[0] + f[1]*f[1] + f[2]*f[2] + f[3]*f[3];
        ss = blockSum256(ss, tid);
        const float scale = rsqrtf(ss * (1.f / DMODEL) + 1e-6f);
        const float4 wv = *(const float4*)(n1w + tid * 4);
        const float wa[4] = { wv.x, wv.y, wv.z, wv.w };
        bf16x4 o;
        #pragma unroll
        for (int j = 0; j < 4; ++j) o[j] = (bf16)(f[j] * scale * wa[j]);
        *(bf16x4*)(h1 + (size_t)row * DMODEL + tid * 4) = o;
        return;
    }
    const float* in; bf16* out; int L, tC, R, C;
    if (gb < TSEG0)      { in = s0; out = d0; L = gb;         tC = 130; R = 1024; C = 4160; }
    else if (gb < TSEG1) { in = s1; out = d1; L = gb - TSEG0; tC = 32;  R = 2048; C = 1024; }
    else if (gb < TSEG2) { in = s2; out = d2; L = gb - TSEG1; tC = 128; R = 1024; C = 4096; }
    else                 { in = s3; out = d3; L = gb - TSEG2; tC = 32;  R = 4096; C = 1024; }
    const int bx = (L % tC) * 32, by = (L / tC) * 32;
    __shared__ float t[32][33];
    #pragma unroll
    for (int i = 0; i < 4; ++i)
        t[ty + i * 8][tx] = in[(size_t)(by + ty + i * 8) * C + bx + tx];
    __syncthreads();
    #pragma unroll
    for (int i = 0; i < 4; ++i)
        out[(size_t)(bx + ty + i * 8) * R + by + tx] = (bf16)t[tx][ty + i * 8];
}

// ======== 128x128 tile GEMM, BK=64, 2-phase dbuf, 512 threads — R20 skeleton ========
// R21 change: MFMA shape 16x16x32 -> 32x32x16 (2x MACs/instr; µbench 2382 vs 2075 TF).
// Per wave-iter: 8 MFMA (was 16), same 12 ds_read_b128, same staging/sync/LDS.
// Wave tile 32 rows x 64 cols = two 32x32 acc tiles (16 f32 each).
// A frag: row=lane&31, k=(lane>>5)*8+e.  C/D: col=lane&31,
// row=(reg&3)+8*(reg>>2)+4*(lane>>5)  (m74/m101-verified mapping).
// EPI 0: bf16 store + f32 dt side-write   EPI 1: +bias, silu -> bf16
// EPI 2: bf16 split-K partial
template<int EPI>
__global__ __launch_bounds__(512) void gemm_bt(
    const bf16* __restrict__ A, const bf16* __restrict__ BT,
    int M, int N, int K, int nbx, int nby,
    bf16* __restrict__ outb, float* __restrict__ outf,
    const float* __restrict__ bias, float* __restrict__ dtout, size_t pstride)
{
    __shared__ __align__(16) bf16 SH[4][128 * 64];   // [0..1]=A dbuf, [2..3]=B dbuf; 64 KB
    const int nwg = (int)gridDim.x;
    const int wg  = xcd_swz((int)blockIdx.x, nwg);
    const int per = nbx * nby;
    const int sl  = wg / per;                 // split-K slice (0 when no split)
    const int ns  = nwg / per;
    const int w2  = wg % per;
    const int rowstride = nbx * 8;            // G=8 supertile (R20-proven, FETCH -53%)
    const int bx  = (w2 % rowstride) >> 3;
    const int by  = (w2 / rowstride) * 8 + (w2 & 7);
    const int Ks  = K / ns;
    const int kbeg = sl * Ks;

    const int tid  = threadIdx.x;
    const int brow = by * 128;
    const int bcol = bx * 128;
    const int lane = tid & 63;
    const int wid  = tid >> 6;                // 0..7
    const int wm = wid >> 1, wn = wid & 1;    // 4M x 2N: wave owns 32 rows x 64 cols
    const int r32  = lane & 31;
    const int half = lane >> 5;               // k-granule offset within K=16 step

    const int arow  = wm * 32 + r32;
    const int aswz  = arow & 7;
    const int brow0 = wn * 64 + r32;          // col-tile 0
    const int brow1 = wn * 64 + 32 + r32;     // col-tile 1
    const int bswz0 = brow0 & 7;
    const int bswz1 = brow1 & 7;

    f32x16 acc0 = {};
    f32x16 acc1 = {};

    // staging: 1024 granules over 512 threads -> 2 each (identical to R20)
    size_t aoff[2], boff[2];
    #pragma unroll
    for (int i = 0; i < 2; ++i) {
        const int g = tid + i * 512;
        const int srow = g >> 3;
        const int scol = ((g & 7) ^ (srow & 7)) * 8;
        aoff[i] = (size_t)(brow + srow) * K + scol;
        int bn = bcol + srow; if (bn > N - 1) bn = N - 1;
        boff[i] = (size_t)bn * K + scol;
    }

    auto stage = [&](int buf, int k0) {
        #pragma unroll
        for (int i = 0; i < 2; ++i) {
            gload_lds16(A + aoff[i] + k0, SH[buf] + (tid + i * 512) * 8);
            gload_lds16(BT + boff[i] + k0, SH[2 + buf] + (tid + i * 512) * 8);
        }
    };

    const int nt = Ks >> 6;
    stage(0, kbeg);
    __syncthreads();
    for (int t = 0; t < nt; ++t) {
        const int cur = t & 1;
        if (t + 1 < nt) stage(cur ^ 1, kbeg + (t + 1) * 64);
        #pragma unroll
        for (int kk = 0; kk < 4; ++kk) {      // 4 x K=16 steps per BK=64
            const int g = kk * 2 + half;      // k-granule 0..7
            const bf16x8 af  = *(const bf16x8*)(SH[cur]     + arow  * 64 + ((g ^ aswz)  << 3));
            const bf16x8 bf0 = *(const bf16x8*)(SH[2 + cur] + brow0 * 64 + ((g ^ bswz0) << 3));
            const bf16x8 bf1 = *(const bf16x8*)(SH[2 + cur] + brow1 * 64 + ((g ^ bswz1) << 3));
            acc0 = __builtin_amdgcn_mfma_f32_32x32x16_bf16(af, bf0, acc0, 0, 0, 0);
            acc1 = __builtin_amdgcn_mfma_f32_32x32x16_bf16(af, bf1, acc1, 0, 0, 0);
        }
        __syncthreads();
    }

    // ---- dt side-channel straight from acc (EPI 0, last block-column only) ----
    if constexpr (EPI == 0) {
        if (bcol + 128 > DTOFF) {
            #pragma unroll
            for (int ct = 0; ct < 2; ++ct) {
                const int gcol = bcol + wn * 64 + ct * 32 + r32;
                if (gcol < DTOFF || gcol >= N) continue;
                #pragma unroll
                for (int reg = 0; reg < 16; ++reg) {
                    const int row = brow + wm * 32 + (reg & 3) + 8 * (reg >> 2) + 4 * half;
                    const float v = ct ? acc1[reg] : acc0[reg];
                    dtout[(size_t)row * NH + (gcol - DTOFF)] = v;
                }
            }
        }
    }

    // ---- LDS-repack epilogue: acc -> Cs[128][132] (bf16) -> 16-B coalesced stores ----
    bf16* Cs = &SH[0][0];                      // 128*132*2 = 33792 B
    #pragma unroll
    for (int ct = 0; ct < 2; ++ct) {
        const int c = wn * 64 + ct * 32 + r32;
        #pragma unroll
        for (int reg = 0; reg < 16; ++reg) {
            const int r0 = wm * 32 + (reg & 3) + 8 * (reg >> 2) + 4 * half;
            float v = ct ? acc1[reg] : acc0[reg];
            if constexpr (EPI == 1) {
                v += bias[bcol + c];
                v = v * sigmoidf_(v);
            }
            Cs[r0 * 132 + c] = (bf16)v;
        }
    }
    __syncthreads();
    #pragma unroll
    for (int i = 0; i < 4; ++i) {
        const int chunk = tid + i * 512;       // 2048 chunks = 128 rows x 16
        const int r = chunk >> 4;
        const int c = (chunk & 15) * 8;
        const int gcol = bcol + c;
        if (gcol >= N) continue;               // N % 8 == 0 for all our shapes
        const bf16x8 val = *(const bf16x8*)(Cs + r * 132 + c);
        const size_t idx = (size_t)(brow + r) * N + gcol;
        if constexpr (EPI == 2) *(bf16x8*)(outb + pstride * sl + idx) = val;
        else                    *(bf16x8*)(outb + idx) = val;
    }
}

// ---- fused: x2 = part[0]+part[1] + x ; h2 = rmsnorm(x2, w) -> bf16 ----
__global__ __launch_bounds__(256) void reduce_norm_k(const bf16* __restrict__ part,
                                                     const float* __restrict__ res,
                                                     const float* __restrict__ w,
                                                     float* __restrict__ x2,
                                                     bf16* __restrict__ h2) {
    const int row = blockIdx.x, tid = threadIdx.x;
    const size_t MN = (size_t)ROWS * DMODEL;
    const size_t i = (size_t)row * DMODEL + tid * 4;
    const bf16x4 a = *(const bf16x4*)(part + i);
    const bf16x4 b = *(const bf16x4*)(part + MN + i);
    const float4 r = *(const float4*)(res + i);
    const float ra[4] = { r.x, r.y, r.z, r.w };
    float f[4];
    #pragma unroll
    for (int j = 0; j < 4; ++j) f[j] = (float)a[j] + (float)b[j] + ra[j];
    *(float4*)(x2 + i) = make_float4(f[0], f[1], f[2], f[3]);
    float ss = f[0]*f[0] + f[1]*f[1] + f[2]*f[2] + f[3]*f[3];
    ss = blockSum256(ss, tid);
    const float scale = rsqrtf(ss * (1.f / DMODEL) + 1e-6f);
    const float4 wv = *(const float4*)(w + tid * 4);
    const float wa[4] = { wv.x, wv.y, wv.z, wv.w };
    bf16x4 o;
    #pragma unroll
    for (int j = 0; j < 4; ++j) o[j] = (bf16)(f[j] * scale * wa[j]);
    *(bf16x4*)(h2 + i) = o;
}

// ---------------- split-K final reduce: out = part[0]+part[1] + res + bias ----------------
__global__ __launch_bounds__(256) void reduce_k(const bf16* __restrict__ part,
                                                const float* __restrict__ res,
                                                const float* __restrict__ bias,
                                                float* __restrict__ out, int MN) {
    const int i = (blockIdx.x * 256 + threadIdx.x) * 4;
    if (i >= MN) return;
    const bf16x4 a = *(const bf16x4*)(part + i);
    const bf16x4 b = *(const bf16x4*)(part + (size_t)MN + i);
    const float4 r = *(const float4*)(res + i);
    const float ra[4] = { r.x, r.y, r.z, r.w };
    const int col = i & (DMODEL - 1);
    float o[4];
    #pragma unroll
    for (int j = 0; j < 4; ++j) o[j] = (float)a[j] + (float)b[j] + ra[j] + bias[col + j];
    *(float4*)(out + i) = make_float4(o[0], o[1], o[2], o[3]);
}

// y (bf16) gated by silu(z) (z cols of zx, bf16), rmsnorm eps 1e-5
__global__ __launch_bounds__(256) void rmsgate_k(const bf16* __restrict__ y,
                                                 const bf16* __restrict__ zx,
                                                 const float* __restrict__ w,
                                                 bf16* __restrict__ out) {
    const int row = blockIdx.x, tid = threadIdx.x;
    const bf16* yr = y + (size_t)row * DINNER;
    const bf16* zr = zx + (size_t)row * DPROJ;
    float vals[8];
    float ss = 0.f;
    #pragma unroll
    for (int i = 0; i < 2; ++i) {
        const bf16x4 yv = *(const bf16x4*)(yr + tid * 8 + i * 4);
        const bf16x4 zv = *(const bf16x4*)(zr + tid * 8 + i * 4);
        #pragma unroll
        for (int j = 0; j < 4; ++j) {
            const float z = (float)zv[j];
            const float t = (float)yv[j] * (z * sigmoidf_(z));
            vals[i * 4 + j] = t;
            ss += t * t;
        }
    }
    ss = blockSum256(ss, tid);
    const float scale = rsqrtf(ss * (1.f / DINNER) + 1e-5f);
    bf16* orow = out + (size_t)row * DINNER + tid * 8;
    #pragma unroll
    for (int i = 0; i < 2; ++i) {
        bf16x4 o;
        #pragma unroll
        for (int j = 0; j < 4; ++j)
            o[j] = (bf16)(vals[i * 4 + j] * scale * w[tid * 8 + i * 4 + j]);
        *(bf16x4*)(orow + i * 4) = o;
    }
}

// --- merged: causal depthwise conv (K=3)+silu -> bf16, and dt/dA precompute ---
#define CONV_TOT (ROWS * CONVD)
#define DT_TOT   (ROWS * NH)
__global__ __launch_bounds__(256) void conv_dtda_k(const bf16* __restrict__ zx,
                                                   const float* __restrict__ cw,
                                                   const float* __restrict__ cb,
                                                   bf16* __restrict__ xBC,
                                                   const float* __restrict__ dtraw,
                                                   const float* __restrict__ dt_bias,
                                                   const float* __restrict__ A_log,
                                                   float* __restrict__ dtb,
                                                   float* __restrict__ dab) {
    const int idx = blockIdx.x * 256 + threadIdx.x;
    if (idx < CONV_TOT) {
        const int c  = idx % CONVD;
        const int bl = idx / CONVD;
        const int l  = bl % SEQ;
        float acc = cb[c];
        const bf16* col = zx + (size_t)bl * DPROJ + DINNER + c;
        if (l >= 2) acc += cw[c * 3 + 0] * (float)col[-2 * DPROJ];
        if (l >= 1) acc += cw[c * 3 + 1] * (float)col[-1 * DPROJ];
        acc += cw[c * 3 + 2] * (float)col[0];
        acc = acc * sigmoidf_(acc);
        xBC[(size_t)bl * CONVD + c] = (bf16)acc;
    } else {
        const int j = idx - CONV_TOT;
        if (j >= DT_TOT) return;
        const int h = j & (NH - 1);
        const float raw = dtraw[j] + dt_bias[h];
        const float dt = raw > 20.f ? raw : log1pf(expf(raw));
        const float dA = expf(-expf(A_log[h]) * dt);
        dtb[j] = dt;
        dab[j] = dA;
    }
}

// ---------------- chunked scan, phase 1: local scan -> S_loc, P ----------------
__global__ __launch_bounds__(256) void scan1_k(const bf16* __restrict__ xBC,
                                               const float* __restrict__ dtb,
                                               const float* __restrict__ dab,
                                               float* __restrict__ Sloc,
                                               float* __restrict__ Pc) {
    const int c = blockIdx.x & (NCHUNK - 1);
    const int h = (blockIdx.x >> 5) & (NH - 1);
    const int b = blockIdx.x >> 10;
    const int tid = threadIdx.x;
    const int p  = tid >> 2;
    const int nq = (tid & 3) * 4;
    const size_t rb = (size_t)b * SEQ + c * CS;
    const bf16* xrow = xBC + rb * CONVD + h * HD + p;
    const bf16* Brow = xBC + rb * CONVD + DINNER + nq;
    const float* dtp = dtb + rb * NH + h;
    const float* dap = dab + rb * NH + h;
    float s0 = 0.f, s1 = 0.f, s2 = 0.f, s3 = 0.f, P = 1.f;
    for (int l = 0; l < CS; ++l) {
        const float xv  = (float)xrow[(size_t)l * CONVD];
        const bf16x4 Bv = *(const bf16x4*)(Brow + (size_t)l * CONVD);
        const float dtv = dtp[l * NH];
        const float dav = dap[l * NH];
        const float xdt = xv * dtv;
        s0 = s0 * dav + xdt * (float)Bv[0];
        s1 = s1 * dav + xdt * (float)Bv[1];
        s2 = s2 * dav + xdt * (float)Bv[2];
        s3 = s3 * dav + xdt * (float)Bv[3];
        P *= dav;
    }
    float4* dst = (float4*)(Sloc + (size_t)blockIdx.x * 1024 + tid * 4);
    *dst = make_float4(s0, s1, s2, s3);
    if (tid == 0) Pc[blockIdx.x] = P;
}

// ---------------- phase 2: carry scan over chunks ----------------
__global__ __launch_bounds__(256) void scan2_k(const float* __restrict__ Sloc,
                                               const float* __restrict__ Pc,
                                               float* __restrict__ Sini) {
    const int bh = blockIdx.x;
    const int tid = threadIdx.x;
    const size_t base = (size_t)bh * NCHUNK;
    float c0 = 0.f, c1 = 0.f, c2 = 0.f, c3 = 0.f;
    for (int c = 0; c < NCHUNK; ++c) {
        *(float4*)(Sini + (base + c) * 1024 + tid * 4) = make_float4(c0, c1, c2, c3);
        const float4 sl = *(const float4*)(Sloc + (base + c) * 1024 + tid * 4);
        const float P = Pc[base + c];
        c0 = c0 * P + sl.x;
        c1 = c1 * P + sl.y;
        c2 = c2 * P + sl.z;
        c3 = c3 * P + sl.w;
    }
}

// ---------------- phase 3: local scan with carried init, emit y (bf16) ----------------
__global__ __launch_bounds__(256) void scan3_k(const bf16* __restrict__ xBC,
                                               const float* __restrict__ dtb,
                                               const float* __restrict__ dab,
                                               const float* __restrict__ Dp,
                                               const float* __restrict__ Sini,
                                               bf16* __restrict__ y) {
    const int c = blockIdx.x & (NCHUNK - 1);
    const int h = (blockIdx.x >> 5) & (NH - 1);
    const int b = blockIdx.x >> 10;
    const int tid = threadIdx.x;
    const int p  = tid >> 2;
    const int nq = (tid & 3) * 4;
    const float Dh = Dp[h];
    const size_t rb = (size_t)b * SEQ + c * CS;
    const bf16* xrow = xBC + rb * CONVD + h * HD + p;
    const bf16* Brow = xBC + rb * CONVD + DINNER + nq;
    const bf16* Crow = xBC + rb * CONVD + DINNER + DSTATE + nq;
    const float* dtp = dtb + rb * NH + h;
    const float* dap = dab + rb * NH + h;
    bf16* yp = y + rb * DINNER + h * HD + p;
    const float4 si = *(const float4*)(Sini + (size_t)blockIdx.x * 1024 + tid * 4);
    float s0 = si.x, s1 = si.y, s2 = si.z, s3 = si.w;
    for (int l = 0; l < CS; ++l) {
        const float xv  = (float)xrow[(size_t)l * CONVD];
        const bf16x4 Bv = *(const bf16x4*)(Brow + (size_t)l * CONVD);
        const bf16x4 Cv = *(const bf16x4*)(Crow + (size_t)l * CONVD);
        const float dtv = dtp[l * NH];
        const float dav = dap[l * NH];
        const float xdt = xv * dtv;
        s0 = s0 * dav + xdt * (float)Bv[0];
        s1 = s1 * dav + xdt * (float)Bv[1];
        s2 = s2 * dav + xdt * (float)Bv[2];
        s3 = s3 * dav + xdt * (float)Bv[3];
        float part = s0 * (float)Cv[0] + s1 * (float)Cv[1] + s2 * (float)Cv[2] + s3 * (float)Cv[3];
        part += __shfl_xor(part, 1);
        part += __shfl_xor(part, 2);
        if ((tid & 3) == 0) yp[(size_t)l * DINNER] = (bf16)(part + Dh * xv);
    }
}

// ---------------- host launch ----------------
extern "C" void kernel_launch(void* const* d_in, const int* in_sizes, int n_in,
                              void* d_out, int out_size, void* d_ws, size_t ws_size,
                              hipStream_t stream) {
    const float* x       = (const float*)d_in[0];
    const float* n1w     = (const float*)d_in[1];
    const float* W_in    = (const float*)d_in[2];
    const float* conv_w  = (const float*)d_in[3];
    const float* conv_b  = (const float*)d_in[4];
    const float* dt_bias = (const float*)d_in[5];
    const float* A_log   = (const float*)d_in[6];
    const float* Dp      = (const float*)d_in[7];
    const float* ngw     = (const float*)d_in[8];
    const float* W_out   = (const float*)d_in[9];
    const float* n2w     = (const float*)d_in[10];
    const float* w1      = (const float*)d_in[11];
    const float* b1      = (const float*)d_in[12];
    const float* w2      = (const float*)d_in[13];
    const float* b2      = (const float*)d_in[14];
    float* out = (float*)d_out;

    char* p = (char*)d_ws;
    auto alloc = [&](size_t bytes) -> char* {
        char* q = p;
        p += (bytes + 255) & ~(size_t)255;
        return q;
    };
    bf16*  W_inT  = (bf16*) alloc((size_t)DPROJ  * DMODEL * 2);
    bf16*  W_outT = (bf16*) alloc((size_t)DMODEL * DINNER * 2);
    bf16*  w1T    = (bf16*) alloc((size_t)DMLP   * DMODEL * 2);
    bf16*  w2T    = (bf16*) alloc((size_t)DMODEL * DMLP   * 2);
    bf16*  h1     = (bf16*) alloc((size_t)ROWS * DMODEL * 2);
    bf16*  zx     = (bf16*) alloc((size_t)ROWS * DPROJ  * 2);   // aliased as split-K partials later
    float* dtraw  = (float*)alloc((size_t)ROWS * NH * 4);
    bf16*  xBC    = (bf16*) alloc((size_t)ROWS * CONVD * 2);
    float* dtb    = (float*)alloc((size_t)ROWS * NH * 4);
    float* dab    = (float*)alloc((size_t)ROWS * NH * 4);
    bf16*  ybuf   = (bf16*) alloc((size_t)ROWS * DINNER * 2);
    bf16*  ynorm  = (bf16*) alloc((size_t)ROWS * DINNER * 2);
    float* x2     = (float*)alloc((size_t)ROWS * DMODEL * 4);
    bf16*  h2     = (bf16*) alloc((size_t)ROWS * DMODEL * 2);
    bf16*  mid    = (bf16*) alloc((size_t)ROWS * DMLP * 2);
    float* Sloc   = (float*)alloc((size_t)BATCH * NH * NCHUNK * 1024 * 4);
    float* Sini   = (float*)alloc((size_t)BATCH * NH * NCHUNK * 1024 * 4);
    float* Pc     = (float*)alloc((size_t)BATCH * NH * NCHUNK * 4);
    // split-K partials (bf16): 2 * 4096*1024 * 2B = 16.8 MB, aliased over zx
    bf16*  part   = zx;
    const size_t pstride = (size_t)ROWS * DMODEL;
    (void)ws_size; (void)in_sizes; (void)n_in; (void)out_size;

    // 4 weight transposes + rmsnorm1, one launch
    front_k<<<TSEG4, dim3(32, 8), 0, stream>>>(
        W_in, W_inT, W_out, W_outT, w1, w1T, w2, w2T, x, n1w, h1);

    // zx = h1 @ W_in  (128^2 BK=64 dbuf, 512 thr, 32x32x16 MFMA) + f32 dt side-channel
    gemm_bt<0><<<33 * 32, 512, 0, stream>>>(
        h1, W_inT, ROWS, DPROJ, DMODEL, 33, 32, zx, nullptr, nullptr, dtraw, 0);

    // conv+silu and dt/dA, one launch
    conv_dtda_k<<<(CONV_TOT + DT_TOT + 255) / 256, 256, 0, stream>>>(
        zx, conv_w, conv_b, xBC, dtraw, dt_bias, A_log, dtb, dab);

    scan1_k<<<BATCH * NH * NCHUNK, 256, 0, stream>>>(xBC, dtb, dab, Sloc, Pc);
    scan2_k<<<BATCH * NH, 256, 0, stream>>>(Sloc, Pc, Sini);
    scan3_k<<<BATCH * NH * NCHUNK, 256, 0, stream>>>(xBC, dtb, dab, Dp, Sini, ybuf);

    rmsgate_k<<<ROWS, 256, 0, stream>>>(ybuf, zx, ngw, ynorm);
    // ---- zx / dtraw dead from here; zx reused as bf16 split-K partials ----

    // part = ynorm @ W_out  (split-K=2, bf16 partials), then fused reduce+norm
    gemm_bt<2><<<8 * 32 * NSPLIT, 512, 0, stream>>>(
        ynorm, W_outT, ROWS, DMODEL, DINNER, 8, 32, part, nullptr, nullptr, nullptr, pstride);
    reduce_norm_k<<<ROWS, 256, 0, stream>>>(part, x, n2w, x2, h2);

    // mid = silu(h2 @ w1 + b1)
    gemm_bt<1><<<32 * 32, 512, 0, stream>>>(
        h2, w1T, ROWS, DMLP, DMODEL, 32, 32, mid, nullptr, b1, nullptr, 0);

    // out = x2 + mid @ w2 + b2  (split-K=2, bf16 partials)
    gemm_bt<2><<<8 * 32 * NSPLIT, 512, 0, stream>>>(
        mid, w2T, ROWS, DMODEL, DMLP, 8, 32, part, nullptr, nullptr, nullptr, pstride);
    reduce_k<<<(ROWS * DMODEL / 4 + 255) / 256, 256, 0, stream>>>(
        part, x2, b2, out, ROWS * DMODEL);
}

// Round 22
// 299.188 us; speedup vs baseline: 1.0585x; 1.0585x over previous
//
#include <hip/hip_runtime.h>

typedef __bf16 bf16;
typedef __bf16 bf16x4 __attribute__((ext_vector_type(4)));
typedef __bf16 bf16x8 __attribute__((ext_vector_type(8)));
typedef float  f32x4  __attribute__((ext_vector_type(4)));

#define BATCH  2
#define SEQ    2048
#define ROWS   (BATCH*SEQ)     // 4096
#define DMODEL 1024
#define DINNER 2048
#define DSTATE 16
#define NH     32
#define HD     64
#define CONVD  2080
#define DPROJ  4160
#define DMLP   4096
#define DTOFF  (DINNER + CONVD)   // 4128
#define CS     64                 // scan chunk size
#define NCHUNK (SEQ/CS)           // 32
#define NSPLIT 2                  // split-K slices for N=1024 GEMMs

__device__ __forceinline__ float sigmoidf_(float x) { return 1.f / (1.f + expf(-x)); }

__device__ __forceinline__ float blockSum256(float v, int tid) {
    #pragma unroll
    for (int o = 32; o > 0; o >>= 1) v += __shfl_down(v, o);
    __shared__ float sb[4];
    if ((tid & 63) == 0) sb[tid >> 6] = v;
    __syncthreads();
    return sb[0] + sb[1] + sb[2] + sb[3];
}

__device__ __forceinline__ void gload_lds16(const bf16* g, bf16* l) {
    __builtin_amdgcn_global_load_lds((const __attribute__((address_space(1))) void*)g,
                                     (__attribute__((address_space(3))) void*)l, 16, 0, 0);
}

// bijective XCD-chunk swizzle (m204)
__device__ __forceinline__ int xcd_swz(int orig, int nwg) {
    const int q = nwg >> 3, r = nwg & 7;
    const int x = orig & 7, i = orig >> 3;
    return (x < r ? x * (q + 1) : r * (q + 1) + (x - r) * q) + i;
}

// --- merged front kernel: 4 weight transposes + rmsnorm1, segmented 1D grid ---
#define TSEG0 4160
#define TSEG1 (TSEG0 + 2048)   // 6208
#define TSEG2 (TSEG1 + 4096)   // 10304
#define TSEG3 (TSEG2 + 4096)   // 14400
#define TSEG4 (TSEG3 + ROWS)   // 18496  (rmsnorm1 rows)
__global__ __launch_bounds__(256) void front_k(
    const float* __restrict__ s0, bf16* __restrict__ d0,
    const float* __restrict__ s1, bf16* __restrict__ d1,
    const float* __restrict__ s2, bf16* __restrict__ d2,
    const float* __restrict__ s3, bf16* __restrict__ d3,
    const float* __restrict__ x,  const float* __restrict__ n1w,
    bf16* __restrict__ h1)
{
    const int gb = blockIdx.x;
    const int tx = threadIdx.x, ty = threadIdx.y;   // block (32,8)
    if (gb >= TSEG3) {
        // ---- rmsnorm1: one row per block, flat 256 threads ----
        const int row = gb - TSEG3;
        const int tid = ty * 32 + tx;
        const float4 v = *(const float4*)(x + (size_t)row * DMODEL + tid * 4);
        float f[4] = { v.x, v.y, v.z, v.w };
        float ss = f[0]*f[0] + f[1]*f[1] + f[2]*f[2] + f[3]*f[3];
        ss = blockSum256(ss, tid);
        const float scale = rsqrtf(ss * (1.f / DMODEL) + 1e-6f);
        const float4 wv = *(const float4*)(n1w + tid * 4);
        const float wa[4] = { wv.x, wv.y, wv.z, wv.w };
        bf16x4 o;
        #pragma unroll
        for (int j = 0; j < 4; ++j) o[j] = (bf16)(f[j] * scale * wa[j]);
        *(bf16x4*)(h1 + (size_t)row * DMODEL + tid * 4) = o;
        return;
    }
    const float* in; bf16* out; int L, tC, R, C;
    if (gb < TSEG0)      { in = s0; out = d0; L = gb;         tC = 130; R = 1024; C = 4160; }
    else if (gb < TSEG1) { in = s1; out = d1; L = gb - TSEG0; tC = 32;  R = 2048; C = 1024; }
    else if (gb < TSEG2) { in = s2; out = d2; L = gb - TSEG1; tC = 128; R = 1024; C = 4096; }
    else                 { in = s3; out = d3; L = gb - TSEG2; tC = 32;  R = 4096; C = 1024; }
    const int bx = (L % tC) * 32, by = (L / tC) * 32;
    __shared__ float t[32][33];
    #pragma unroll
    for (int i = 0; i < 4; ++i)
        t[ty + i * 8][tx] = in[(size_t)(by + ty + i * 8) * C + bx + tx];
    __syncthreads();
    #pragma unroll
    for (int i = 0; i < 4; ++i)
        out[(size_t)(bx + ty + i * 8) * R + by + tx] = (bf16)t[tx][ty + i * 8];
}

// ======== 128x128 tile GEMM, BK=64, 2-phase dbuf, 512 threads — R20 measured optimum ========
// 64 KB LDS -> 2 blocks/CU x 8 waves = 16 waves/CU (saturation point of the
// measured occupancy curve). 16x16x32 MFMA with conflict-free 8-slot XOR swizzle.
// G=8 supertiled XCD map (FETCH 70 -> 33 MB). LDS-repack coalesced epilogue.
// EPI 0: bf16 store + f32 dt side-write   EPI 1: +bias, silu -> bf16
// EPI 2: bf16 split-K partial
template<int EPI>
__global__ __launch_bounds__(512) void gemm_bt(
    const bf16* __restrict__ A, const bf16* __restrict__ BT,
    int M, int N, int K, int nbx, int nby,
    bf16* __restrict__ outb, float* __restrict__ outf,
    const float* __restrict__ bias, float* __restrict__ dtout, size_t pstride)
{
    __shared__ __align__(16) bf16 SH[4][128 * 64];   // [0..1]=A dbuf, [2..3]=B dbuf; 64 KB
    const int nwg = (int)gridDim.x;
    const int wg  = xcd_swz((int)blockIdx.x, nwg);
    const int per = nbx * nby;
    const int sl  = wg / per;                 // split-K slice (0 when no split)
    const int ns  = nwg / per;
    const int w2  = wg % per;
    const int rowstride = nbx * 8;            // G=8 supertile
    const int bx  = (w2 % rowstride) >> 3;
    const int by  = (w2 / rowstride) * 8 + (w2 & 7);
    const int Ks  = K / ns;
    const int kbeg = sl * Ks;

    const int tid  = threadIdx.x;
    const int brow = by * 128;
    const int bcol = bx * 128;
    const int lane = tid & 63;
    const int wid  = tid >> 6;                // 0..7
    const int wm = wid >> 1, wn = wid & 1;    // 4M x 2N: wave owns 32 rows x 64 cols
    const int lr = lane & 15, lk = lane >> 4;
    const int X  = lr & 7;
    const int off0 = ((lk) ^ X) * 8;
    const int off1 = ((4 + lk) ^ X) * 8;

    f32x4 acc[2][4] = {};

    // staging: 1024 granules over 512 threads -> 2 each
    size_t aoff[2], boff[2];
    #pragma unroll
    for (int i = 0; i < 2; ++i) {
        const int g = tid + i * 512;
        const int srow = g >> 3;
        const int scol = ((g & 7) ^ (srow & 7)) * 8;
        aoff[i] = (size_t)(brow + srow) * K + scol;
        int bn = bcol + srow; if (bn > N - 1) bn = N - 1;
        boff[i] = (size_t)bn * K + scol;
    }

    auto stage = [&](int buf, int k0) {
        #pragma unroll
        for (int i = 0; i < 2; ++i) {
            gload_lds16(A + aoff[i] + k0, SH[buf] + (tid + i * 512) * 8);
            gload_lds16(BT + boff[i] + k0, SH[2 + buf] + (tid + i * 512) * 8);
        }
    };

    const int nt = Ks >> 6;
    stage(0, kbeg);
    __syncthreads();
    for (int t = 0; t < nt; ++t) {
        const int cur = t & 1;
        if (t + 1 < nt) stage(cur ^ 1, kbeg + (t + 1) * 64);
        #pragma unroll
        for (int kk = 0; kk < 2; ++kk) {
            const int off = kk ? off1 : off0;
            bf16x8 af[2], bfr[4];
            #pragma unroll
            for (int m = 0; m < 2; ++m)
                af[m] = *(const bf16x8*)(SH[cur] + (wm * 32 + m * 16 + lr) * 64 + off);
            #pragma unroll
            for (int n = 0; n < 4; ++n)
                bfr[n] = *(const bf16x8*)(SH[2 + cur] + (wn * 64 + n * 16 + lr) * 64 + off);
            #pragma unroll
            for (int m = 0; m < 2; ++m)
                #pragma unroll
                for (int n = 0; n < 4; ++n)
                    acc[m][n] = __builtin_amdgcn_mfma_f32_16x16x32_bf16(af[m], bfr[n], acc[m][n], 0, 0, 0);
        }
        __syncthreads();
    }

    // ---- dt side-channel straight from acc (EPI 0, last block-column only) ----
    if constexpr (EPI == 0) {
        if (bcol + 128 > DTOFF) {
            #pragma unroll
            for (int m = 0; m < 2; ++m) {
                const int grow = brow + wm * 32 + m * 16 + lk * 4;
                #pragma unroll
                for (int n = 0; n < 4; ++n) {
                    const int gcol = bcol + wn * 64 + n * 16 + lr;
                    if (gcol < DTOFF || gcol >= N) continue;
                    #pragma unroll
                    for (int j = 0; j < 4; ++j)
                        dtout[(size_t)(grow + j) * NH + (gcol - DTOFF)] = acc[m][n][j];
                }
            }
        }
    }

    // ---- LDS-repack epilogue: acc -> Cs[128][132] (bf16) -> 16-B coalesced stores ----
    bf16* Cs = &SH[0][0];                      // 128*132*2 = 33792 B
    #pragma unroll
    for (int m = 0; m < 2; ++m) {
        const int r0 = wm * 32 + m * 16 + lk * 4;
        #pragma unroll
        for (int n = 0; n < 4; ++n) {
            const int c = wn * 64 + n * 16 + lr;
            #pragma unroll
            for (int j = 0; j < 4; ++j) {
                float v = acc[m][n][j];
                if constexpr (EPI == 1) {
                    v += bias[bcol + c];
                    v = v * sigmoidf_(v);
                }
                Cs[(r0 + j) * 132 + c] = (bf16)v;
            }
        }
    }
    __syncthreads();
    #pragma unroll
    for (int i = 0; i < 4; ++i) {
        const int chunk = tid + i * 512;       // 2048 chunks = 128 rows x 16
        const int r = chunk >> 4;
        const int c = (chunk & 15) * 8;
        const int gcol = bcol + c;
        if (gcol >= N) continue;               // N % 8 == 0 for all our shapes
        const bf16x8 val = *(const bf16x8*)(Cs + r * 132 + c);
        const size_t idx = (size_t)(brow + r) * N + gcol;
        if constexpr (EPI == 2) *(bf16x8*)(outb + pstride * sl + idx) = val;
        else                    *(bf16x8*)(outb + idx) = val;
    }
}

// ---- fused: x2 = part[0]+part[1] + x ; h2 = rmsnorm(x2, w) -> bf16 ----
__global__ __launch_bounds__(256) void reduce_norm_k(const bf16* __restrict__ part,
                                                     const float* __restrict__ res,
                                                     const float* __restrict__ w,
                                                     float* __restrict__ x2,
                                                     bf16* __restrict__ h2) {
    const int row = blockIdx.x, tid = threadIdx.x;
    const size_t MN = (size_t)ROWS * DMODEL;
    const size_t i = (size_t)row * DMODEL + tid * 4;
    const bf16x4 a = *(const bf16x4*)(part + i);
    const bf16x4 b = *(const bf16x4*)(part + MN + i);
    const float4 r = *(const float4*)(res + i);
    const float ra[4] = { r.x, r.y, r.z, r.w };
    float f[4];
    #pragma unroll
    for (int j = 0; j < 4; ++j) f[j] = (float)a[j] + (float)b[j] + ra[j];
    *(float4*)(x2 + i) = make_float4(f[0], f[1], f[2], f[3]);
    float ss = f[0]*f[0] + f[1]*f[1] + f[2]*f[2] + f[3]*f[3];
    ss = blockSum256(ss, tid);
    const float scale = rsqrtf(ss * (1.f / DMODEL) + 1e-6f);
    const float4 wv = *(const float4*)(w + tid * 4);
    const float wa[4] = { wv.x, wv.y, wv.z, wv.w };
    bf16x4 o;
    #pragma unroll
    for (int j = 0; j < 4; ++j) o[j] = (bf16)(f[j] * scale * wa[j]);
    *(bf16x4*)(h2 + i) = o;
}

// ---------------- split-K final reduce: out = part[0]+part[1] + res + bias ----------------
__global__ __launch_bounds__(256) void reduce_k(const bf16* __restrict__ part,
                                                const float* __restrict__ res,
                                                const float* __restrict__ bias,
                                                float* __restrict__ out, int MN) {
    const int i = (blockIdx.x * 256 + threadIdx.x) * 4;
    if (i >= MN) return;
    const bf16x4 a = *(const bf16x4*)(part + i);
    const bf16x4 b = *(const bf16x4*)(part + (size_t)MN + i);
    const float4 r = *(const float4*)(res + i);
    const float ra[4] = { r.x, r.y, r.z, r.w };
    const int col = i & (DMODEL - 1);
    float o[4];
    #pragma unroll
    for (int j = 0; j < 4; ++j) o[j] = (float)a[j] + (float)b[j] + ra[j] + bias[col + j];
    *(float4*)(out + i) = make_float4(o[0], o[1], o[2], o[3]);
}

// y (bf16) gated by silu(z) (z cols of zx, bf16), rmsnorm eps 1e-5
__global__ __launch_bounds__(256) void rmsgate_k(const bf16* __restrict__ y,
                                                 const bf16* __restrict__ zx,
                                                 const float* __restrict__ w,
                                                 bf16* __restrict__ out) {
    const int row = blockIdx.x, tid = threadIdx.x;
    const bf16* yr = y + (size_t)row * DINNER;
    const bf16* zr = zx + (size_t)row * DPROJ;
    float vals[8];
    float ss = 0.f;
    #pragma unroll
    for (int i = 0; i < 2; ++i) {
        const bf16x4 yv = *(const bf16x4*)(yr + tid * 8 + i * 4);
        const bf16x4 zv = *(const bf16x4*)(zr + tid * 8 + i * 4);
        #pragma unroll
        for (int j = 0; j < 4; ++j) {
            const float z = (float)zv[j];
            const float t = (float)yv[j] * (z * sigmoidf_(z));
            vals[i * 4 + j] = t;
            ss += t * t;
        }
    }
    ss = blockSum256(ss, tid);
    const float scale = rsqrtf(ss * (1.f / DINNER) + 1e-5f);
    bf16* orow = out + (size_t)row * DINNER + tid * 8;
    #pragma unroll
    for (int i = 0; i < 2; ++i) {
        bf16x4 o;
        #pragma unroll
        for (int j = 0; j < 4; ++j)
            o[j] = (bf16)(vals[i * 4 + j] * scale * w[tid * 8 + i * 4 + j]);
        *(bf16x4*)(orow + i * 4) = o;
    }
}

// --- merged: causal depthwise conv (K=3)+silu -> bf16, and dt/dA precompute ---
#define CONV_TOT (ROWS * CONVD)
#define DT_TOT   (ROWS * NH)
__global__ __launch_bounds__(256) void conv_dtda_k(const bf16* __restrict__ zx,
                                                   const float* __restrict__ cw,
                                                   const float* __restrict__ cb,
                                                   bf16* __restrict__ xBC,
                                                   const float* __restrict__ dtraw,
                                                   const float* __restrict__ dt_bias,
                                                   const float* __restrict__ A_log,
                                                   float* __restrict__ dtb,
                                                   float* __restrict__ dab) {
    const int idx = blockIdx.x * 256 + threadIdx.x;
    if (idx < CONV_TOT) {
        const int c  = idx % CONVD;
        const int bl = idx / CONVD;
        const int l  = bl % SEQ;
        float acc = cb[c];
        const bf16* col = zx + (size_t)bl * DPROJ + DINNER + c;
        if (l >= 2) acc += cw[c * 3 + 0] * (float)col[-2 * DPROJ];
        if (l >= 1) acc += cw[c * 3 + 1] * (float)col[-1 * DPROJ];
        acc += cw[c * 3 + 2] * (float)col[0];
        acc = acc * sigmoidf_(acc);
        xBC[(size_t)bl * CONVD + c] = (bf16)acc;
    } else {
        const int j = idx - CONV_TOT;
        if (j >= DT_TOT) return;
        const int h = j & (NH - 1);
        const float raw = dtraw[j] + dt_bias[h];
        const float dt = raw > 20.f ? raw : log1pf(expf(raw));
        const float dA = expf(-expf(A_log[h]) * dt);
        dtb[j] = dt;
        dab[j] = dA;
    }
}

// ---------------- chunked scan, phase 1: local scan -> S_loc, P ----------------
__global__ __launch_bounds__(256) void scan1_k(const bf16* __restrict__ xBC,
                                               const float* __restrict__ dtb,
                                               const float* __restrict__ dab,
                                               float* __restrict__ Sloc,
                                               float* __restrict__ Pc) {
    const int c = blockIdx.x & (NCHUNK - 1);
    const int h = (blockIdx.x >> 5) & (NH - 1);
    const int b = blockIdx.x >> 10;
    const int tid = threadIdx.x;
    const int p  = tid >> 2;
    const int nq = (tid & 3) * 4;
    const size_t rb = (size_t)b * SEQ + c * CS;
    const bf16* xrow = xBC + rb * CONVD + h * HD + p;
    const bf16* Brow = xBC + rb * CONVD + DINNER + nq;
    const float* dtp = dtb + rb * NH + h;
    const float* dap = dab + rb * NH + h;
    float s0 = 0.f, s1 = 0.f, s2 = 0.f, s3 = 0.f, P = 1.f;
    for (int l = 0; l < CS; ++l) {
        const float xv  = (float)xrow[(size_t)l * CONVD];
        const bf16x4 Bv = *(const bf16x4*)(Brow + (size_t)l * CONVD);
        const float dtv = dtp[l * NH];
        const float dav = dap[l * NH];
        const float xdt = xv * dtv;
        s0 = s0 * dav + xdt * (float)Bv[0];
        s1 = s1 * dav + xdt * (float)Bv[1];
        s2 = s2 * dav + xdt * (float)Bv[2];
        s3 = s3 * dav + xdt * (float)Bv[3];
        P *= dav;
    }
    float4* dst = (float4*)(Sloc + (size_t)blockIdx.x * 1024 + tid * 4);
    *dst = make_float4(s0, s1, s2, s3);
    if (tid == 0) Pc[blockIdx.x] = P;
}

// ---------------- phase 2: carry scan over chunks ----------------
__global__ __launch_bounds__(256) void scan2_k(const float* __restrict__ Sloc,
                                               const float* __restrict__ Pc,
                                               float* __restrict__ Sini) {
    const int bh = blockIdx.x;
    const int tid = threadIdx.x;
    const size_t base = (size_t)bh * NCHUNK;
    float c0 = 0.f, c1 = 0.f, c2 = 0.f, c3 = 0.f;
    for (int c = 0; c < NCHUNK; ++c) {
        *(float4*)(Sini + (base + c) * 1024 + tid * 4) = make_float4(c0, c1, c2, c3);
        const float4 sl = *(const float4*)(Sloc + (base + c) * 1024 + tid * 4);
        const float P = Pc[base + c];
        c0 = c0 * P + sl.x;
        c1 = c1 * P + sl.y;
        c2 = c2 * P + sl.z;
        c3 = c3 * P + sl.w;
    }
}

// ---------------- phase 3: local scan with carried init, emit y (bf16) ----------------
__global__ __launch_bounds__(256) void scan3_k(const bf16* __restrict__ xBC,
                                               const float* __restrict__ dtb,
                                               const float* __restrict__ dab,
                                               const float* __restrict__ Dp,
                                               const float* __restrict__ Sini,
                                               bf16* __restrict__ y) {
    const int c = blockIdx.x & (NCHUNK - 1);
    const int h = (blockIdx.x >> 5) & (NH - 1);
    const int b = blockIdx.x >> 10;
    const int tid = threadIdx.x;
    const int p  = tid >> 2;
    const int nq = (tid & 3) * 4;
    const float Dh = Dp[h];
    const size_t rb = (size_t)b * SEQ + c * CS;
    const bf16* xrow = xBC + rb * CONVD + h * HD + p;
    const bf16* Brow = xBC + rb * CONVD + DINNER + nq;
    const bf16* Crow = xBC + rb * CONVD + DINNER + DSTATE + nq;
    const float* dtp = dtb + rb * NH + h;
    const float* dap = dab + rb * NH + h;
    bf16* yp = y + rb * DINNER + h * HD + p;
    const float4 si = *(const float4*)(Sini + (size_t)blockIdx.x * 1024 + tid * 4);
    float s0 = si.x, s1 = si.y, s2 = si.z, s3 = si.w;
    for (int l = 0; l < CS; ++l) {
        const float xv  = (float)xrow[(size_t)l * CONVD];
        const bf16x4 Bv = *(const bf16x4*)(Brow + (size_t)l * CONVD);
        const bf16x4 Cv = *(const bf16x4*)(Crow + (size_t)l * CONVD);
        const float dtv = dtp[l * NH];
        const float dav = dap[l * NH];
        const float xdt = xv * dtv;
        s0 = s0 * dav + xdt * (float)Bv[0];
        s1 = s1 * dav + xdt * (float)Bv[1];
        s2 = s2 * dav + xdt * (float)Bv[2];
        s3 = s3 * dav + xdt * (float)Bv[3];
        float part = s0 * (float)Cv[0] + s1 * (float)Cv[1] + s2 * (float)Cv[2] + s3 * (float)Cv[3];
        part += __shfl_xor(part, 1);
        part += __shfl_xor(part, 2);
        if ((tid & 3) == 0) yp[(size_t)l * DINNER] = (bf16)(part + Dh * xv);
    }
}

// ---------------- host launch ----------------
extern "C" void kernel_launch(void* const* d_in, const int* in_sizes, int n_in,
                              void* d_out, int out_size, void* d_ws, size_t ws_size,
                              hipStream_t stream) {
    const float* x       = (const float*)d_in[0];
    const float* n1w     = (const float*)d_in[1];
    const float* W_in    = (const float*)d_in[2];
    const float* conv_w  = (const float*)d_in[3];
    const float* conv_b  = (const float*)d_in[4];
    const float* dt_bias = (const float*)d_in[5];
    const float* A_log   = (const float*)d_in[6];
    const float* Dp      = (const float*)d_in[7];
    const float* ngw     = (const float*)d_in[8];
    const float* W_out   = (const float*)d_in[9];
    const float* n2w     = (const float*)d_in[10];
    const float* w1      = (const float*)d_in[11];
    const float* b1      = (const float*)d_in[12];
    const float* w2      = (const float*)d_in[13];
    const float* b2      = (const float*)d_in[14];
    float* out = (float*)d_out;

    char* p = (char*)d_ws;
    auto alloc = [&](size_t bytes) -> char* {
        char* q = p;
        p += (bytes + 255) & ~(size_t)255;
        return q;
    };
    bf16*  W_inT  = (bf16*) alloc((size_t)DPROJ  * DMODEL * 2);
    bf16*  W_outT = (bf16*) alloc((size_t)DMODEL * DINNER * 2);
    bf16*  w1T    = (bf16*) alloc((size_t)DMLP   * DMODEL * 2);
    bf16*  w2T    = (bf16*) alloc((size_t)DMODEL * DMLP   * 2);
    bf16*  h1     = (bf16*) alloc((size_t)ROWS * DMODEL * 2);
    bf16*  zx     = (bf16*) alloc((size_t)ROWS * DPROJ  * 2);   // aliased as split-K partials later
    float* dtraw  = (float*)alloc((size_t)ROWS * NH * 4);
    bf16*  xBC    = (bf16*) alloc((size_t)ROWS * CONVD * 2);
    float* dtb    = (float*)alloc((size_t)ROWS * NH * 4);
    float* dab    = (float*)alloc((size_t)ROWS * NH * 4);
    bf16*  ybuf   = (bf16*) alloc((size_t)ROWS * DINNER * 2);
    bf16*  ynorm  = (bf16*) alloc((size_t)ROWS * DINNER * 2);
    float* x2     = (float*)alloc((size_t)ROWS * DMODEL * 4);
    bf16*  h2     = (bf16*) alloc((size_t)ROWS * DMODEL * 2);
    bf16*  mid    = (bf16*) alloc((size_t)ROWS * DMLP * 2);
    float* Sloc   = (float*)alloc((size_t)BATCH * NH * NCHUNK * 1024 * 4);
    float* Sini   = (float*)alloc((size_t)BATCH * NH * NCHUNK * 1024 * 4);
    float* Pc     = (float*)alloc((size_t)BATCH * NH * NCHUNK * 4);
    // split-K partials (bf16): 2 * 4096*1024 * 2B = 16.8 MB, aliased over zx
    bf16*  part   = zx;
    const size_t pstride = (size_t)ROWS * DMODEL;
    (void)ws_size; (void)in_sizes; (void)n_in; (void)out_size;

    // 4 weight transposes + rmsnorm1, one launch
    front_k<<<TSEG4, dim3(32, 8), 0, stream>>>(
        W_in, W_inT, W_out, W_outT, w1, w1T, w2, w2T, x, n1w, h1);

    // zx = h1 @ W_in  (128^2 BK=64 dbuf, 512 thr, supertiled map) + f32 dt side-channel
    gemm_bt<0><<<33 * 32, 512, 0, stream>>>(
        h1, W_inT, ROWS, DPROJ, DMODEL, 33, 32, zx, nullptr, nullptr, dtraw, 0);

    // conv+silu and dt/dA, one launch
    conv_dtda_k<<<(CONV_TOT + DT_TOT + 255) / 256, 256, 0, stream>>>(
        zx, conv_w, conv_b, xBC, dtraw, dt_bias, A_log, dtb, dab);

    scan1_k<<<BATCH * NH * NCHUNK, 256, 0, stream>>>(xBC, dtb, dab, Sloc, Pc);
    scan2_k<<<BATCH * NH, 256, 0, stream>>>(Sloc, Pc, Sini);
    scan3_k<<<BATCH * NH * NCHUNK, 256, 0, stream>>>(xBC, dtb, dab, Dp, Sini, ybuf);

    rmsgate_k<<<ROWS, 256, 0, stream>>>(ybuf, zx, ngw, ynorm);
    // ---- zx / dtraw dead from here; zx reused as bf16 split-K partials ----

    // part = ynorm @ W_out  (split-K=2, bf16 partials), then fused reduce+norm
    gemm_bt<2><<<8 * 32 * NSPLIT, 512, 0, stream>>>(
        ynorm, W_outT, ROWS, DMODEL, DINNER, 8, 32, part, nullptr, nullptr, nullptr, pstride);
    reduce_norm_k<<<ROWS, 256, 0, stream>>>(part, x, n2w, x2, h2);

    // mid = silu(h2 @ w1 + b1)
    gemm_bt<1><<<32 * 32, 512, 0, stream>>>(
        h2, w1T, ROWS, DMLP, DMODEL, 32, 32, mid, nullptr, b1, nullptr, 0);

    // out = x2 + mid @ w2 + b2  (split-K=2, bf16 partials)
    gemm_bt<2><<<8 * 32 * NSPLIT, 512, 0, stream>>>(
        mid, w2T, ROWS, DMODEL, DMLP, 8, 32, part, nullptr, nullptr, nullptr, pstride);
    reduce_k<<<(ROWS * DMODEL / 4 + 255) / 256, 256, 0, stream>>>(
        part, x2, b2, out, ROWS * DMODEL);
}